// Round 1
// baseline (2713.673 us; speedup 1.0000x reference)
//
#include <hip/hip_runtime.h>
#include <math.h>

#define NLVL 10
#define ND 4

// Compile-time hash-grid geometry (matches reference setup).
constexpr int      kRes[NLVL]  = {16, 32, 64, 128, 256, 512, 1024, 2048, 4096, 8192};
constexpr unsigned kSize[NLVL] = {4920u, 35944u, 274632u, 2097152u, 2097152u,
                                  2097152u, 2097152u, 2097152u, 2097152u, 2097152u};
constexpr unsigned kOff[NLVL]  = {0u, 4920u, 40864u, 315496u, 2412648u,
                                  4509800u, 6606952u, 8704104u, 10801256u, 12898408u};

// ---------------------------------------------------------------------------
// Kernel A: hash-grid encode + erf weighting + mean over the 6 sub-points.
// One thread per (sample, level). Writes features[N][40] (layout l*4+d).
// ---------------------------------------------------------------------------
template <int LVL>
__device__ __forceinline__ void hash_level(int i,
                                           const float* __restrict__ means,
                                           const float* __restrict__ stds,
                                           const float* __restrict__ emb,
                                           float* __restrict__ feats) {
    constexpr float    res = (float)kRes[LVL];
    constexpr unsigned sz  = kSize[LVL];
    const float* __restrict__ embL = emb + (size_t)kOff[LVL] * 4;

    float a0 = 0.f, a1 = 0.f, a2 = 0.f, a3 = 0.f;
#pragma unroll 1
    for (int j = 0; j < 6; ++j) {
        const float* mp = means + ((size_t)i * 6 + j) * 3;
        float mx = mp[0], my = mp[1], mz = mp[2];
        float s = stds[i * 6 + j];
        // erf(1/sqrt(8*s^2*r^2)) = erf(1/(2*sqrt(2)*s*r))
        float w = erff(1.0f / (2.8284271247461903f * s * res));

        float px = (mx + 1.0f) * 0.5f * res + 0.5f;
        float py = (my + 1.0f) * 0.5f * res + 0.5f;
        float pz = (mz + 1.0f) * 0.5f * res + 0.5f;
        float flx = floorf(px), fly = floorf(py), flz = floorf(pz);
        float fx = px - flx, fy = py - fly, fz = pz - flz;
        unsigned bx = (unsigned)(int)flx;
        unsigned by = (unsigned)(int)fly;
        unsigned bz = (unsigned)(int)flz;

        unsigned hx0 = bx,                 hx1 = bx + 1u;
        unsigned hy0 = by * 2654435761u,   hy1 = (by + 1u) * 2654435761u;
        unsigned hz0 = bz * 805459861u,    hz1 = (bz + 1u) * 805459861u;
        float wx0 = 1.f - fx, wy0 = 1.f - fy, wz0 = 1.f - fz;

#pragma unroll
        for (int c = 0; c < 8; ++c) {
            unsigned h = ((c & 1) ? hx1 : hx0) ^ ((c & 2) ? hy1 : hy0) ^
                         ((c & 4) ? hz1 : hz0);
            unsigned idx = h % sz;  // sz is constexpr -> magic-mul, or & mask for pow2
            const float4 g = *reinterpret_cast<const float4*>(embL + (size_t)idx * 4);
            float wc = w * ((c & 1) ? fx : wx0) * ((c & 2) ? fy : wy0) *
                       ((c & 4) ? fz : wz0);
            a0 = fmaf(wc, g.x, a0);
            a1 = fmaf(wc, g.y, a1);
            a2 = fmaf(wc, g.z, a2);
            a3 = fmaf(wc, g.w, a3);
        }
    }
    constexpr float inv6 = 1.0f / 6.0f;
    float4 o;
    o.x = a0 * inv6; o.y = a1 * inv6; o.z = a2 * inv6; o.w = a3 * inv6;
    *reinterpret_cast<float4*>(feats + (size_t)i * 40 + LVL * 4) = o;
}

__global__ void __launch_bounds__(256) hash_kernel(int N,
                                                   const float* __restrict__ means,
                                                   const float* __restrict__ stds,
                                                   const float* __restrict__ emb,
                                                   float* __restrict__ feats) {
    int i = blockIdx.x * 256 + threadIdx.x;
    if (i >= N) return;
    switch (blockIdx.y) {
        case 0: hash_level<0>(i, means, stds, emb, feats); break;
        case 1: hash_level<1>(i, means, stds, emb, feats); break;
        case 2: hash_level<2>(i, means, stds, emb, feats); break;
        case 3: hash_level<3>(i, means, stds, emb, feats); break;
        case 4: hash_level<4>(i, means, stds, emb, feats); break;
        case 5: hash_level<5>(i, means, stds, emb, feats); break;
        case 6: hash_level<6>(i, means, stds, emb, feats); break;
        case 7: hash_level<7>(i, means, stds, emb, feats); break;
        case 8: hash_level<8>(i, means, stds, emb, feats); break;
        case 9: hash_level<9>(i, means, stds, emb, feats); break;
    }
}

// ---------------------------------------------------------------------------
// Kernel B: fully-fused MLP. 16 samples per 256-thread workgroup.
// Activations in LDS; weights streamed from global (L1/L2-resident),
// each weight element reused across 16 samples in registers.
// ---------------------------------------------------------------------------
__global__ void __launch_bounds__(256) mlp_kernel(
    int N, const float* __restrict__ feats, const float* __restrict__ dirs,
    const float* __restrict__ W1, const float* __restrict__ b1,
    const float* __restrict__ W2, const float* __restrict__ b2,
    const float* __restrict__ Wv0, const float* __restrict__ bv0,
    const float* __restrict__ Wv1, const float* __restrict__ bv1,
    const float* __restrict__ Wrgb, const float* __restrict__ brgb,
    float* __restrict__ rgb_out, float* __restrict__ dens_out) {
    __shared__ float sFeat[16 * 40];   // features
    __shared__ float sInp[16][284];    // [0..255]=x (layer2 out), [256..282]=dir_enc
    __shared__ float sH1[16][64];      // layer1 out
    __shared__ float sH[16][256];      // v0 out, then v1 out

    const int t = threadIdx.x;
    const int s0 = blockIdx.x * 16;
    if (s0 >= N) return;

    // stage features (contiguous 640 floats)
    for (int k = t; k < 640; k += 256) sFeat[k] = feats[(size_t)s0 * 40 + k];

    // dir encoding: threads 0..15, one sample each
    if (t < 16) {
        const float* vp = dirs + (size_t)(s0 + t) * 3;
        float vx = vp[0], vy = vp[1], vz = vp[2];
        sInp[t][256] = vx; sInp[t][257] = vy; sInp[t][258] = vz;
#pragma unroll
        for (int q = 0; q < 4; ++q) {
            float sc = (float)(1 << q);
            sInp[t][259 + q * 3 + 0] = sinf(vx * sc);
            sInp[t][259 + q * 3 + 1] = sinf(vy * sc);
            sInp[t][259 + q * 3 + 2] = sinf(vz * sc);
            sInp[t][271 + q * 3 + 0] = cosf(vx * sc);
            sInp[t][271 + q * 3 + 1] = cosf(vy * sc);
            sInp[t][271 + q * 3 + 2] = cosf(vz * sc);
        }
    }
    __syncthreads();

    // ---- layer 1: 40 -> 64, relu. thread = (neuron t&63, sample-group t>>6)
    {
        const int n = t & 63;
        const int g = t >> 6;  // 4 samples each
        float acc[4] = {0.f, 0.f, 0.f, 0.f};
        for (int k = 0; k < 40; ++k) {
            float w = W1[k * 64 + n];
#pragma unroll
            for (int ss = 0; ss < 4; ++ss)
                acc[ss] = fmaf(w, sFeat[(g * 4 + ss) * 40 + k], acc[ss]);
        }
        float bb = b1[n];
#pragma unroll
        for (int ss = 0; ss < 4; ++ss)
            sH1[g * 4 + ss][n] = fmaxf(acc[ss] + bb, 0.f);
    }
    __syncthreads();

    // ---- layer 2: 64 -> 256, NO relu. thread = neuron t, 16 samples.
    {
        float acc[16];
#pragma unroll
        for (int s = 0; s < 16; ++s) acc[s] = 0.f;
        for (int k = 0; k < 64; ++k) {
            float w = W2[k * 256 + t];
#pragma unroll
            for (int s = 0; s < 16; ++s) acc[s] = fmaf(w, sH1[s][k], acc[s]);
        }
        float bb = b2[t];
#pragma unroll
        for (int s = 0; s < 16; ++s) sInp[s][t] = acc[s] + bb;
    }
    __syncthreads();

    // ---- view layer 0: 283 -> 256, relu
    {
        float acc[16];
#pragma unroll
        for (int s = 0; s < 16; ++s) acc[s] = 0.f;
        for (int k = 0; k < 283; ++k) {
            float w = Wv0[k * 256 + t];
#pragma unroll
            for (int s = 0; s < 16; ++s) acc[s] = fmaf(w, sInp[s][k], acc[s]);
        }
        float bb = bv0[t];
#pragma unroll
        for (int s = 0; s < 16; ++s) sH[s][t] = fmaxf(acc[s] + bb, 0.f);
    }
    __syncthreads();

    // ---- view layer 1: concat(h,inp) 539 -> 256, relu
    {
        float acc[16];
#pragma unroll
        for (int s = 0; s < 16; ++s) acc[s] = 0.f;
        for (int k = 0; k < 256; ++k) {
            float w = Wv1[k * 256 + t];
#pragma unroll
            for (int s = 0; s < 16; ++s) acc[s] = fmaf(w, sH[s][k], acc[s]);
        }
        for (int k = 0; k < 283; ++k) {
            float w = Wv1[(256 + k) * 256 + t];
#pragma unroll
            for (int s = 0; s < 16; ++s) acc[s] = fmaf(w, sInp[s][k], acc[s]);
        }
        float bb = bv1[t];
        __syncthreads();  // all reads of sH done before overwrite
#pragma unroll
        for (int s = 0; s < 16; ++s) sH[s][t] = fmaxf(acc[s] + bb, 0.f);
    }
    __syncthreads();

    // ---- heads
    if (t < 48) {
        int s = t / 3, c = t - s * 3;
        float acc = 0.f;
        for (int k = 0; k < 256; ++k) acc = fmaf(sH[s][k], Wrgb[k * 3 + c], acc);
        float v = acc + brgb[c];
        float sg = 1.f / (1.f + expf(-v));
        rgb_out[(size_t)(s0 + s) * 3 + c] = sg * 1.002f - 0.001f;
    } else if (t < 64) {
        int s = t - 48;
        float z = sInp[s][0] - 1.0f;  // raw_density + DENSITY_BIAS
        float sp = (z > 20.f) ? z : log1pf(expf(z));
        dens_out[s0 + s] = sp;
    }
}

// ---------------------------------------------------------------------------
extern "C" void kernel_launch(void* const* d_in, const int* in_sizes, int n_in,
                              void* d_out, int out_size, void* d_ws, size_t ws_size,
                              hipStream_t stream) {
    const float* means = (const float*)d_in[1];
    const float* stds  = (const float*)d_in[2];
    const float* dirs  = (const float*)d_in[3];
    const float* emb   = (const float*)d_in[5];
    const float* W1   = (const float*)d_in[6];
    const float* b1   = (const float*)d_in[7];
    const float* W2   = (const float*)d_in[8];
    const float* b2   = (const float*)d_in[9];
    const float* Wv0  = (const float*)d_in[10];
    const float* bv0  = (const float*)d_in[11];
    const float* Wv1  = (const float*)d_in[12];
    const float* bv1  = (const float*)d_in[13];
    const float* Wrgb = (const float*)d_in[14];
    const float* brgb = (const float*)d_in[15];

    const int N = in_sizes[1] / 18;  // means: [N,6,3]
    float* feats = (float*)d_ws;     // N*40 floats
    float* out   = (float*)d_out;    // rgb [N*3] then density [N]

    dim3 gridA((N + 255) / 256, NLVL);
    hash_kernel<<<gridA, 256, 0, stream>>>(N, means, stds, emb, feats);

    mlp_kernel<<<(N + 15) / 16, 256, 0, stream>>>(
        N, feats, dirs, W1, b1, W2, b2, Wv0, bv0, Wv1, bv1, Wrgb, brgb,
        out, out + (size_t)3 * N);
}

// Round 2
// 1881.983 us; speedup vs baseline: 1.4419x; 1.4419x over previous
//
#include <hip/hip_runtime.h>
#include <math.h>

#define NLVL 10

// Compile-time hash-grid geometry (matches reference setup).
constexpr int      kRes[NLVL]  = {16, 32, 64, 128, 256, 512, 1024, 2048, 4096, 8192};
constexpr unsigned kSize[NLVL] = {4920u, 35944u, 274632u, 2097152u, 2097152u,
                                  2097152u, 2097152u, 2097152u, 2097152u, 2097152u};
constexpr unsigned kOff[NLVL]  = {0u, 4920u, 40864u, 315496u, 2412648u,
                                  4509800u, 6606952u, 8704104u, 10801256u, 12898408u};

// ---------------------------------------------------------------------------
// Kernel A: hash-grid encode + erf weighting + mean over the 6 sub-points.
// One thread per (sample, level). Writes features[N][40] (layout l*4+d).
// ---------------------------------------------------------------------------
template <int LVL>
__device__ __forceinline__ void hash_level(int i,
                                           const float* __restrict__ means,
                                           const float* __restrict__ stds,
                                           const float* __restrict__ emb,
                                           float* __restrict__ feats) {
    constexpr float    res = (float)kRes[LVL];
    constexpr unsigned sz  = kSize[LVL];
    const float* __restrict__ embL = emb + (size_t)kOff[LVL] * 4;

    float a0 = 0.f, a1 = 0.f, a2 = 0.f, a3 = 0.f;
#pragma unroll 1
    for (int j = 0; j < 6; ++j) {
        const float* mp = means + ((size_t)i * 6 + j) * 3;
        float mx = mp[0], my = mp[1], mz = mp[2];
        float s = stds[i * 6 + j];
        // erf(1/sqrt(8*s^2*r^2)) = erf(1/(2*sqrt(2)*s*r))
        float w = erff(1.0f / (2.8284271247461903f * s * res));

        float px = (mx + 1.0f) * 0.5f * res + 0.5f;
        float py = (my + 1.0f) * 0.5f * res + 0.5f;
        float pz = (mz + 1.0f) * 0.5f * res + 0.5f;
        float flx = floorf(px), fly = floorf(py), flz = floorf(pz);
        float fx = px - flx, fy = py - fly, fz = pz - flz;
        unsigned bx = (unsigned)(int)flx;
        unsigned by = (unsigned)(int)fly;
        unsigned bz = (unsigned)(int)flz;

        unsigned hx0 = bx,                 hx1 = bx + 1u;
        unsigned hy0 = by * 2654435761u,   hy1 = (by + 1u) * 2654435761u;
        unsigned hz0 = bz * 805459861u,    hz1 = (bz + 1u) * 805459861u;
        float wx0 = 1.f - fx, wy0 = 1.f - fy, wz0 = 1.f - fz;

#pragma unroll
        for (int c = 0; c < 8; ++c) {
            unsigned h = ((c & 1) ? hx1 : hx0) ^ ((c & 2) ? hy1 : hy0) ^
                         ((c & 4) ? hz1 : hz0);
            unsigned idx = h % sz;  // constexpr -> magic-mul
            const float4 g = *reinterpret_cast<const float4*>(embL + (size_t)idx * 4);
            float wc = w * ((c & 1) ? fx : wx0) * ((c & 2) ? fy : wy0) *
                       ((c & 4) ? fz : wz0);
            a0 = fmaf(wc, g.x, a0);
            a1 = fmaf(wc, g.y, a1);
            a2 = fmaf(wc, g.z, a2);
            a3 = fmaf(wc, g.w, a3);
        }
    }
    constexpr float inv6 = 1.0f / 6.0f;
    float4 o;
    o.x = a0 * inv6; o.y = a1 * inv6; o.z = a2 * inv6; o.w = a3 * inv6;
    *reinterpret_cast<float4*>(feats + (size_t)i * 40 + LVL * 4) = o;
}

__global__ void __launch_bounds__(256) hash_kernel(int N,
                                                   const float* __restrict__ means,
                                                   const float* __restrict__ stds,
                                                   const float* __restrict__ emb,
                                                   float* __restrict__ feats) {
    int i = blockIdx.x * 256 + threadIdx.x;
    if (i >= N) return;
    switch (blockIdx.y) {
        case 0: hash_level<0>(i, means, stds, emb, feats); break;
        case 1: hash_level<1>(i, means, stds, emb, feats); break;
        case 2: hash_level<2>(i, means, stds, emb, feats); break;
        case 3: hash_level<3>(i, means, stds, emb, feats); break;
        case 4: hash_level<4>(i, means, stds, emb, feats); break;
        case 5: hash_level<5>(i, means, stds, emb, feats); break;
        case 6: hash_level<6>(i, means, stds, emb, feats); break;
        case 7: hash_level<7>(i, means, stds, emb, feats); break;
        case 8: hash_level<8>(i, means, stds, emb, feats); break;
        case 9: hash_level<9>(i, means, stds, emb, feats); break;
    }
}

// ---------------------------------------------------------------------------
// Kernel B: fully-fused MLP. 16 samples per 256-thread workgroup.
// All LDS activation reads are wave-uniform broadcasts; vectorized to
// ds_read_b128 (float4) so the LDS pipe issues 4x fewer instructions.
// LDS kept under 40 KB (sFeat/sH1 aliased into the sH buffer) -> 4 WG/CU.
// ---------------------------------------------------------------------------
__global__ void __launch_bounds__(256) mlp_kernel(
    int N, const float* __restrict__ feats, const float* __restrict__ dirs,
    const float* __restrict__ W1, const float* __restrict__ b1,
    const float* __restrict__ W2, const float* __restrict__ b2,
    const float* __restrict__ Wv0, const float* __restrict__ bv0,
    const float* __restrict__ Wv1, const float* __restrict__ bv1,
    const float* __restrict__ Wrgb, const float* __restrict__ brgb,
    float* __restrict__ rgb_out, float* __restrict__ dens_out) {
    __shared__ float sInp[16][284];    // [0..255]=x (layer2 out), [256..282]=dir_enc
    __shared__ float sBuf[16][256];    // union: {sFeat[640], sH1[16][64]} then sH[16][256]

    float* sFeat = &sBuf[0][0];                              // 640 floats
    float (*sH1)[64]  = (float(*)[64])(&sBuf[0][0] + 704);   // 16x64, 16B-aligned
    float (*sH)[256]  = sBuf;                                // live after layer2

    const int t = threadIdx.x;
    const int s0 = blockIdx.x * 16;
    if (s0 >= N) return;

    // stage features (contiguous 640 floats)
    for (int k = t; k < 640; k += 256) sFeat[k] = feats[(size_t)s0 * 40 + k];

    // dir encoding: threads 0..15, one sample each
    if (t < 16) {
        const float* vp = dirs + (size_t)(s0 + t) * 3;
        float vx = vp[0], vy = vp[1], vz = vp[2];
        sInp[t][256] = vx; sInp[t][257] = vy; sInp[t][258] = vz;
#pragma unroll
        for (int q = 0; q < 4; ++q) {
            float sc = (float)(1 << q);
            sInp[t][259 + q * 3 + 0] = sinf(vx * sc);
            sInp[t][259 + q * 3 + 1] = sinf(vy * sc);
            sInp[t][259 + q * 3 + 2] = sinf(vz * sc);
            sInp[t][271 + q * 3 + 0] = cosf(vx * sc);
            sInp[t][271 + q * 3 + 1] = cosf(vy * sc);
            sInp[t][271 + q * 3 + 2] = cosf(vz * sc);
        }
    }
    __syncthreads();

    // ---- layer 1: 40 -> 64, relu. thread = (neuron t&63, sample-group t>>6)
    {
        const int n = t & 63;
        const int g = t >> 6;  // 4 samples each
        float acc[4] = {0.f, 0.f, 0.f, 0.f};
        for (int k = 0; k < 40; k += 4) {
            float w0 = W1[(k + 0) * 64 + n];
            float w1 = W1[(k + 1) * 64 + n];
            float w2 = W1[(k + 2) * 64 + n];
            float w3 = W1[(k + 3) * 64 + n];
#pragma unroll
            for (int ss = 0; ss < 4; ++ss) {
                const float4 a = *reinterpret_cast<const float4*>(
                    &sFeat[(g * 4 + ss) * 40 + k]);
                acc[ss] = fmaf(w0, a.x, fmaf(w1, a.y, fmaf(w2, a.z,
                          fmaf(w3, a.w, acc[ss]))));
            }
        }
        float bb = b1[n];
#pragma unroll
        for (int ss = 0; ss < 4; ++ss)
            sH1[g * 4 + ss][n] = fmaxf(acc[ss] + bb, 0.f);
    }
    __syncthreads();

    // ---- layer 2: 64 -> 256, NO relu. thread = neuron t, 16 samples.
    {
        float acc[16];
#pragma unroll
        for (int s = 0; s < 16; ++s) acc[s] = 0.f;
        for (int k = 0; k < 64; k += 4) {
            float w0 = W2[(k + 0) * 256 + t];
            float w1 = W2[(k + 1) * 256 + t];
            float w2 = W2[(k + 2) * 256 + t];
            float w3 = W2[(k + 3) * 256 + t];
#pragma unroll
            for (int s = 0; s < 16; ++s) {
                const float4 a = *reinterpret_cast<const float4*>(&sH1[s][k]);
                acc[s] = fmaf(w0, a.x, fmaf(w1, a.y, fmaf(w2, a.z,
                         fmaf(w3, a.w, acc[s]))));
            }
        }
        float bb = b2[t];
#pragma unroll
        for (int s = 0; s < 16; ++s) sInp[s][t] = acc[s] + bb;
    }
    __syncthreads();

    // ---- view layer 0: 283 -> 256, relu. Writes sH (sFeat/sH1 now dead).
    {
        float acc[16];
#pragma unroll
        for (int s = 0; s < 16; ++s) acc[s] = 0.f;
        for (int k = 0; k < 280; k += 4) {
            float w0 = Wv0[(k + 0) * 256 + t];
            float w1 = Wv0[(k + 1) * 256 + t];
            float w2 = Wv0[(k + 2) * 256 + t];
            float w3 = Wv0[(k + 3) * 256 + t];
#pragma unroll
            for (int s = 0; s < 16; ++s) {
                const float4 a = *reinterpret_cast<const float4*>(&sInp[s][k]);
                acc[s] = fmaf(w0, a.x, fmaf(w1, a.y, fmaf(w2, a.z,
                         fmaf(w3, a.w, acc[s]))));
            }
        }
        for (int k = 280; k < 283; ++k) {
            float w = Wv0[k * 256 + t];
#pragma unroll
            for (int s = 0; s < 16; ++s) acc[s] = fmaf(w, sInp[s][k], acc[s]);
        }
        float bb = bv0[t];
#pragma unroll
        for (int s = 0; s < 16; ++s) sH[s][t] = fmaxf(acc[s] + bb, 0.f);
    }
    __syncthreads();

    // ---- view layer 1: concat(h,inp) 539 -> 256, relu
    {
        float acc[16];
#pragma unroll
        for (int s = 0; s < 16; ++s) acc[s] = 0.f;
        for (int k = 0; k < 256; k += 4) {
            float w0 = Wv1[(k + 0) * 256 + t];
            float w1 = Wv1[(k + 1) * 256 + t];
            float w2 = Wv1[(k + 2) * 256 + t];
            float w3 = Wv1[(k + 3) * 256 + t];
#pragma unroll
            for (int s = 0; s < 16; ++s) {
                const float4 a = *reinterpret_cast<const float4*>(&sH[s][k]);
                acc[s] = fmaf(w0, a.x, fmaf(w1, a.y, fmaf(w2, a.z,
                         fmaf(w3, a.w, acc[s]))));
            }
        }
        for (int k = 0; k < 280; k += 4) {
            float w0 = Wv1[(256 + k + 0) * 256 + t];
            float w1 = Wv1[(256 + k + 1) * 256 + t];
            float w2 = Wv1[(256 + k + 2) * 256 + t];
            float w3 = Wv1[(256 + k + 3) * 256 + t];
#pragma unroll
            for (int s = 0; s < 16; ++s) {
                const float4 a = *reinterpret_cast<const float4*>(&sInp[s][k]);
                acc[s] = fmaf(w0, a.x, fmaf(w1, a.y, fmaf(w2, a.z,
                         fmaf(w3, a.w, acc[s]))));
            }
        }
        for (int k = 280; k < 283; ++k) {
            float w = Wv1[(256 + k) * 256 + t];
#pragma unroll
            for (int s = 0; s < 16; ++s) acc[s] = fmaf(w, sInp[s][k], acc[s]);
        }
        float bb = bv1[t];
        __syncthreads();  // all reads of sH done before overwrite
#pragma unroll
        for (int s = 0; s < 16; ++s) sH[s][t] = fmaxf(acc[s] + bb, 0.f);
    }
    __syncthreads();

    // ---- heads
    if (t < 48) {
        int s = t / 3, c = t - s * 3;
        float acc = 0.f;
        for (int k = 0; k < 256; k += 4) {
            const float4 a = *reinterpret_cast<const float4*>(&sH[s][k]);
            acc = fmaf(a.x, Wrgb[(k + 0) * 3 + c],
                  fmaf(a.y, Wrgb[(k + 1) * 3 + c],
                  fmaf(a.z, Wrgb[(k + 2) * 3 + c],
                  fmaf(a.w, Wrgb[(k + 3) * 3 + c], acc))));
        }
        float v = acc + brgb[c];
        float sg = 1.f / (1.f + expf(-v));
        rgb_out[(size_t)(s0 + s) * 3 + c] = sg * 1.002f - 0.001f;
    } else if (t < 64) {
        int s = t - 48;
        float z = sInp[s][0] - 1.0f;  // raw_density + DENSITY_BIAS
        float sp = (z > 20.f) ? z : log1pf(expf(z));
        dens_out[s0 + s] = sp;
    }
}

// ---------------------------------------------------------------------------
extern "C" void kernel_launch(void* const* d_in, const int* in_sizes, int n_in,
                              void* d_out, int out_size, void* d_ws, size_t ws_size,
                              hipStream_t stream) {
    const float* means = (const float*)d_in[1];
    const float* stds  = (const float*)d_in[2];
    const float* dirs  = (const float*)d_in[3];
    const float* emb   = (const float*)d_in[5];
    const float* W1   = (const float*)d_in[6];
    const float* b1   = (const float*)d_in[7];
    const float* W2   = (const float*)d_in[8];
    const float* b2   = (const float*)d_in[9];
    const float* Wv0  = (const float*)d_in[10];
    const float* bv0  = (const float*)d_in[11];
    const float* Wv1  = (const float*)d_in[12];
    const float* bv1  = (const float*)d_in[13];
    const float* Wrgb = (const float*)d_in[14];
    const float* brgb = (const float*)d_in[15];

    const int N = in_sizes[1] / 18;  // means: [N,6,3]
    float* feats = (float*)d_ws;     // N*40 floats
    float* out   = (float*)d_out;    // rgb [N*3] then density [N]

    dim3 gridA((N + 255) / 256, NLVL);
    hash_kernel<<<gridA, 256, 0, stream>>>(N, means, stds, emb, feats);

    mlp_kernel<<<(N + 15) / 16, 256, 0, stream>>>(
        N, feats, dirs, W1, b1, W2, b2, Wv0, bv0, Wv1, bv1, Wrgb, brgb,
        out, out + (size_t)3 * N);
}

// Round 3
// 940.047 us; speedup vs baseline: 2.8867x; 2.0020x over previous
//
#include <hip/hip_runtime.h>
#include <math.h>
#include <stdint.h>

typedef __attribute__((ext_vector_type(8))) short bf16x8;
typedef __attribute__((ext_vector_type(4))) float f32x4;

#define NLVL 10

// Compile-time hash-grid geometry (matches reference setup).
constexpr int      kRes[NLVL]  = {16, 32, 64, 128, 256, 512, 1024, 2048, 4096, 8192};
constexpr unsigned kSize[NLVL] = {4920u, 35944u, 274632u, 2097152u, 2097152u,
                                  2097152u, 2097152u, 2097152u, 2097152u, 2097152u};
constexpr unsigned kOff[NLVL]  = {0u, 4920u, 40864u, 315496u, 2412648u,
                                  4509800u, 6606952u, 8704104u, 10801256u, 12898408u};

// Packed-weight layout in d_ws (ushort element offsets).
// Tiles are 32(K)x16(N), 512 ushorts each; lane l holds
// B[kt*32+(l>>4)*8+j][nt*16+(l&15)], j=0..7 -> one dwordx4 per lane.
constexpr int PU_W1   = 0;        // K40->64 (Kt2), N64  (Nt4) :  8 tiles
constexpr int PU_W2   = 4096;     // K64     (Kt2), N256 (Nt16): 32 tiles
constexpr int PU_WV0  = 20480;    // K283->288 (Kt9), N256     : 144 tiles
constexpr int PU_WV1  = 94208;    // K539->544 (Kt17), N256    : 272 tiles
constexpr int PU_WRGB = 233472;   // K256 (Kt8), N3->16 (Nt1)  :   8 tiles
constexpr int PU_TOTAL = 237568;
constexpr size_t FEATS_BYTE_OFF = (size_t)PU_TOTAL * 2;  // 475136

__device__ __forceinline__ unsigned short f2bf(float f) {
    unsigned u = __builtin_bit_cast(unsigned, f);
    u = u + 0x7FFFu + ((u >> 16) & 1u);   // round-to-nearest-even
    return (unsigned short)(u >> 16);
}

// ---------------------------------------------------------------------------
// Weight pack kernel: f32 row-major [K][N] -> bf16 MFMA tile layout.
// ---------------------------------------------------------------------------
__global__ void __launch_bounds__(256) pack_kernel(
    const float* __restrict__ W1, const float* __restrict__ W2,
    const float* __restrict__ Wv0, const float* __restrict__ Wv1,
    const float* __restrict__ Wrgb, unsigned short* __restrict__ out) {
    int e = blockIdx.x * 256 + threadIdx.x;
    if (e >= PU_TOTAL) return;
    const float* W; int base, K, N, lg;
    if (e < PU_W2)        { W = W1;   base = PU_W1;   K = 40;  N = 64;  lg = 2; }
    else if (e < PU_WV0)  { W = W2;   base = PU_W2;   K = 64;  N = 256; lg = 4; }
    else if (e < PU_WV1)  { W = Wv0;  base = PU_WV0;  K = 283; N = 256; lg = 4; }
    else if (e < PU_WRGB) { W = Wv1;  base = PU_WV1;  K = 539; N = 256; lg = 4; }
    else                  { W = Wrgb; base = PU_WRGB; K = 256; N = 3;   lg = 0; }
    int le = e - base;
    int tile = le >> 9, r = le & 511, lane = r >> 3, j = r & 7;
    int kt = tile >> lg, nt = tile & ((1 << lg) - 1);
    int k = kt * 32 + ((lane >> 4) << 3) + j;
    int n = nt * 16 + (lane & 15);
    float v = (k < K && n < N) ? W[k * N + n] : 0.f;
    out[e] = f2bf(v);
}

// ---------------------------------------------------------------------------
// Kernel A: hash-grid encode (unchanged, fp32 exact).
// ---------------------------------------------------------------------------
template <int LVL>
__device__ __forceinline__ void hash_level(int i,
                                           const float* __restrict__ means,
                                           const float* __restrict__ stds,
                                           const float* __restrict__ emb,
                                           float* __restrict__ feats) {
    constexpr float    res = (float)kRes[LVL];
    constexpr unsigned sz  = kSize[LVL];
    const float* __restrict__ embL = emb + (size_t)kOff[LVL] * 4;

    float a0 = 0.f, a1 = 0.f, a2 = 0.f, a3 = 0.f;
#pragma unroll 1
    for (int j = 0; j < 6; ++j) {
        const float* mp = means + ((size_t)i * 6 + j) * 3;
        float mx = mp[0], my = mp[1], mz = mp[2];
        float s = stds[i * 6 + j];
        float w = erff(1.0f / (2.8284271247461903f * s * res));

        float px = (mx + 1.0f) * 0.5f * res + 0.5f;
        float py = (my + 1.0f) * 0.5f * res + 0.5f;
        float pz = (mz + 1.0f) * 0.5f * res + 0.5f;
        float flx = floorf(px), fly = floorf(py), flz = floorf(pz);
        float fx = px - flx, fy = py - fly, fz = pz - flz;
        unsigned bx = (unsigned)(int)flx;
        unsigned by = (unsigned)(int)fly;
        unsigned bz = (unsigned)(int)flz;

        unsigned hx0 = bx,               hx1 = bx + 1u;
        unsigned hy0 = by * 2654435761u, hy1 = (by + 1u) * 2654435761u;
        unsigned hz0 = bz * 805459861u,  hz1 = (bz + 1u) * 805459861u;
        float wx0 = 1.f - fx, wy0 = 1.f - fy, wz0 = 1.f - fz;

#pragma unroll
        for (int c = 0; c < 8; ++c) {
            unsigned h = ((c & 1) ? hx1 : hx0) ^ ((c & 2) ? hy1 : hy0) ^
                         ((c & 4) ? hz1 : hz0);
            unsigned idx = h % sz;
            const float4 g = *reinterpret_cast<const float4*>(embL + (size_t)idx * 4);
            float wc = w * ((c & 1) ? fx : wx0) * ((c & 2) ? fy : wy0) *
                       ((c & 4) ? fz : wz0);
            a0 = fmaf(wc, g.x, a0);
            a1 = fmaf(wc, g.y, a1);
            a2 = fmaf(wc, g.z, a2);
            a3 = fmaf(wc, g.w, a3);
        }
    }
    constexpr float inv6 = 1.0f / 6.0f;
    float4 o;
    o.x = a0 * inv6; o.y = a1 * inv6; o.z = a2 * inv6; o.w = a3 * inv6;
    *reinterpret_cast<float4*>(feats + (size_t)i * 40 + LVL * 4) = o;
}

__global__ void __launch_bounds__(256) hash_kernel(int N,
                                                   const float* __restrict__ means,
                                                   const float* __restrict__ stds,
                                                   const float* __restrict__ emb,
                                                   float* __restrict__ feats) {
    int i = blockIdx.x * 256 + threadIdx.x;
    if (i >= N) return;
    switch (blockIdx.y) {
        case 0: hash_level<0>(i, means, stds, emb, feats); break;
        case 1: hash_level<1>(i, means, stds, emb, feats); break;
        case 2: hash_level<2>(i, means, stds, emb, feats); break;
        case 3: hash_level<3>(i, means, stds, emb, feats); break;
        case 4: hash_level<4>(i, means, stds, emb, feats); break;
        case 5: hash_level<5>(i, means, stds, emb, feats); break;
        case 6: hash_level<6>(i, means, stds, emb, feats); break;
        case 7: hash_level<7>(i, means, stds, emb, feats); break;
        case 8: hash_level<8>(i, means, stds, emb, feats); break;
        case 9: hash_level<9>(i, means, stds, emb, feats); break;
    }
}

// ---------------------------------------------------------------------------
// Kernel C: exact fp32 density path (layer1 + layer2 column 0 + softplus).
// ---------------------------------------------------------------------------
__global__ void __launch_bounds__(256) density_kernel(
    int N, const float* __restrict__ feats, const float* __restrict__ W1,
    const float* __restrict__ b1, const float* __restrict__ W2,
    const float* __restrict__ b2, float* __restrict__ dens) {
    __shared__ float sW1[2560];
    __shared__ float sb1[64];
    __shared__ float sw2[64];
    int t = threadIdx.x;
    for (int e = t; e < 2560; e += 256) sW1[e] = W1[e];
    if (t < 64) { sb1[t] = b1[t]; sw2[t] = W2[t * 256]; }
    __syncthreads();
    int i = blockIdx.x * 256 + t;
    if (i >= N) return;
    float f[40];
    const float4* fp = (const float4*)(feats + (size_t)i * 40);
#pragma unroll
    for (int q = 0; q < 10; ++q) {
        float4 v = fp[q];
        f[q * 4] = v.x; f[q * 4 + 1] = v.y; f[q * 4 + 2] = v.z; f[q * 4 + 3] = v.w;
    }
    float x0 = 0.f;
#pragma unroll
    for (int n = 0; n < 64; ++n) {
        float h = sb1[n];
#pragma unroll
        for (int k = 0; k < 40; ++k) h = fmaf(f[k], sW1[k * 64 + n], h);
        x0 = fmaf(fmaxf(h, 0.f), sw2[n], x0);
    }
    float z = x0 + b2[0] - 1.0f;
    dens[i] = (z > 20.f) ? z : log1pf(expf(z));
}

// ---------------------------------------------------------------------------
// Kernel B: fused MFMA MLP. 64 samples/block, 4 waves x 16 rows each.
// Each wave owns its rows end-to-end -> no inter-layer barriers.
// B-fragments double-bank prefetched from L2 (prepacked tiles).
// ---------------------------------------------------------------------------
#define LOADB(bank, kt)                                                       \
    { _Pragma("unroll") for (int i_ = 0; i_ < 16; ++i_)                       \
        bank[i_] = *(const bf16x8*)(Bsrc + ((size_t)(kt) * 16 + i_) * 512 +   \
                                    lane * 8); }
#define MFMA16(bank, a)                                                       \
    { _Pragma("unroll") for (int i_ = 0; i_ < 16; ++i_)                       \
        acc[i_] = __builtin_amdgcn_mfma_f32_16x16x32_bf16(a, bank[i_],        \
                                                          acc[i_], 0, 0, 0); }

__device__ __forceinline__ void gemm16(const unsigned short* actRow, int Kt,
                                       const unsigned short* Bsrc, int lane,
                                       f32x4* acc) {
    bf16x8 bankA[16], bankB[16];
    LOADB(bankA, 0);
    int kt = 0;
    while (1) {
        bf16x8 a = *(const bf16x8*)(actRow + kt * 32);
        if (kt + 1 < Kt) LOADB(bankB, kt + 1);
        MFMA16(bankA, a);
        ++kt; if (kt == Kt) break;
        a = *(const bf16x8*)(actRow + kt * 32);
        if (kt + 1 < Kt) LOADB(bankA, kt + 1);
        MFMA16(bankB, a);
        ++kt; if (kt == Kt) break;
    }
}

__global__ void __launch_bounds__(256, 2) mlp_mfma_kernel(
    int N, const float* __restrict__ feats, const float* __restrict__ dirs,
    const unsigned short* __restrict__ pack,
    const float* __restrict__ b1, const float* __restrict__ b2,
    const float* __restrict__ bv0, const float* __restrict__ bv1,
    const float* __restrict__ brgb, float* __restrict__ rgb_out) {
    // row strides 296/264/72: odd multiples of 8 ushorts (16B) -> the 16
    // A-frag rows spread across all bank-groups (conflict-free b128 reads).
    __shared__ __align__(16) unsigned short sInp[64][296]; // [0..255]=x, [256..282]=dir_enc, 283..287=0
    __shared__ __align__(16) unsigned short sHH[64][264];  // v0/v1 out; early: sFeatB+sH1
    unsigned short* sFeatB = &sHH[0][0];                   // [64][72]
    unsigned short* sH1    = &sHH[0][0] + 4608;            // [64][72]

    const int t = threadIdx.x;
    const int w = t >> 6, lane = t & 63;
    const int s0 = blockIdx.x * 64;

    // ---- stage features -> bf16 [64][72], zero K-pad cols 40..63
    {
        int row = t & 63, c0 = (t >> 6) * 10;
        const float* src = feats + (size_t)(s0 + row) * 40 + c0;
#pragma unroll
        for (int c = 0; c < 10; ++c) sFeatB[row * 72 + c0 + c] = f2bf(src[c]);
        int z0 = 40 + (t >> 6) * 6;
#pragma unroll
        for (int c = 0; c < 6; ++c) sFeatB[row * 72 + z0 + c] = 0;
    }
    // ---- dir encoding (rows owned cross-wave -> barrier below)
    if (t < 64) {
        const float* vp = dirs + (size_t)(s0 + t) * 3;
        float vx = vp[0], vy = vp[1], vz = vp[2];
        sInp[t][256] = f2bf(vx); sInp[t][257] = f2bf(vy); sInp[t][258] = f2bf(vz);
#pragma unroll
        for (int q = 0; q < 4; ++q) {
            float sc = (float)(1 << q);
            sInp[t][259 + q * 3 + 0] = f2bf(sinf(vx * sc));
            sInp[t][259 + q * 3 + 1] = f2bf(sinf(vy * sc));
            sInp[t][259 + q * 3 + 2] = f2bf(sinf(vz * sc));
            sInp[t][271 + q * 3 + 0] = f2bf(cosf(vx * sc));
            sInp[t][271 + q * 3 + 1] = f2bf(cosf(vy * sc));
            sInp[t][271 + q * 3 + 2] = f2bf(cosf(vz * sc));
        }
#pragma unroll
        for (int c = 283; c < 288; ++c) sInp[t][c] = 0;
    }
    __syncthreads();  // the only block-wide barrier

    const int rowA  = w * 16 + (lane & 15);   // A-frag row for this lane
    const int kl8   = (lane >> 4) << 3;       // k sub-offset (ushorts)
    const int rbase = w * 16 + ((lane >> 4) << 2);  // C-frag row base
    const int col0  = lane & 15;              // C-frag col within tile

    // ---- layer 1: feats(40->64p) @ W1 -> h1[64], relu
    {
        f32x4 acc1[4];
#pragma unroll
        for (int i = 0; i < 4; ++i) acc1[i] = f32x4{0.f, 0.f, 0.f, 0.f};
        const unsigned short* fRow = sFeatB + (size_t)rowA * 72 + kl8;
        const unsigned short* Bsrc = pack + PU_W1;
#pragma unroll
        for (int kt = 0; kt < 2; ++kt) {
            bf16x8 a = *(const bf16x8*)(fRow + kt * 32);
#pragma unroll
            for (int i = 0; i < 4; ++i) {
                bf16x8 b = *(const bf16x8*)(Bsrc + ((size_t)kt * 4 + i) * 512 + lane * 8);
                acc1[i] = __builtin_amdgcn_mfma_f32_16x16x32_bf16(a, b, acc1[i], 0, 0, 0);
            }
        }
#pragma unroll
        for (int i = 0; i < 4; ++i) {
            float bb = b1[i * 16 + col0];
#pragma unroll
            for (int q = 0; q < 4; ++q)
                sH1[(size_t)(rbase + q) * 72 + i * 16 + col0] =
                    f2bf(fmaxf(acc1[i][q] + bb, 0.f));
        }
    }

    f32x4 acc[16];
    // ---- layer 2: h1(64) @ W2 -> x[256] (no relu) -> sInp cols 0..255
    {
#pragma unroll
        for (int i = 0; i < 16; ++i) acc[i] = f32x4{0.f, 0.f, 0.f, 0.f};
        gemm16(sH1 + (size_t)rowA * 72 + kl8, 2, pack + PU_W2, lane, acc);
#pragma unroll
        for (int i = 0; i < 16; ++i) {
            float bb = b2[i * 16 + col0];
#pragma unroll
            for (int q = 0; q < 4; ++q)
                sInp[rbase + q][i * 16 + col0] = f2bf(acc[i][q] + bb);
        }
    }
    // ---- view layer 0: inp(283->288p) @ Wv0 -> h[256], relu -> sHH
    {
#pragma unroll
        for (int i = 0; i < 16; ++i) acc[i] = f32x4{0.f, 0.f, 0.f, 0.f};
        gemm16(&sInp[0][0] + (size_t)rowA * 296 + kl8, 9, pack + PU_WV0, lane, acc);
#pragma unroll
        for (int i = 0; i < 16; ++i) {
            float bb = bv0[i * 16 + col0];
#pragma unroll
            for (int q = 0; q < 4; ++q)
                sHH[rbase + q][i * 16 + col0] = f2bf(fmaxf(acc[i][q] + bb, 0.f));
        }
    }
    // ---- view layer 1: concat(h[256], inp[283->288p]) @ Wv1 -> relu -> sHH
    {
#pragma unroll
        for (int i = 0; i < 16; ++i) acc[i] = f32x4{0.f, 0.f, 0.f, 0.f};
        gemm16(&sHH[0][0] + (size_t)rowA * 264 + kl8, 8, pack + PU_WV1, lane, acc);
        gemm16(&sInp[0][0] + (size_t)rowA * 296 + kl8, 9, pack + PU_WV1 + 65536, lane, acc);
#pragma unroll
        for (int i = 0; i < 16; ++i) {
            float bb = bv1[i * 16 + col0];
#pragma unroll
            for (int q = 0; q < 4; ++q)
                sHH[rbase + q][i * 16 + col0] = f2bf(fmaxf(acc[i][q] + bb, 0.f));
        }
    }
    // ---- rgb head: h(256) @ Wrgb(256x3p16), sigmoid
    {
        f32x4 accR = f32x4{0.f, 0.f, 0.f, 0.f};
        const unsigned short* hRow = &sHH[0][0] + (size_t)rowA * 264 + kl8;
        const unsigned short* Bsrc = pack + PU_WRGB;
#pragma unroll
        for (int kt = 0; kt < 8; ++kt) {
            bf16x8 a = *(const bf16x8*)(hRow + kt * 32);
            bf16x8 b = *(const bf16x8*)(Bsrc + (size_t)kt * 512 + lane * 8);
            accR = __builtin_amdgcn_mfma_f32_16x16x32_bf16(a, b, accR, 0, 0, 0);
        }
        if (col0 < 3) {
            float bb = brgb[col0];
#pragma unroll
            for (int q = 0; q < 4; ++q) {
                float v = accR[q] + bb;
                float sg = 1.f / (1.f + expf(-v));
                rgb_out[(size_t)(s0 + rbase + q) * 3 + col0] = sg * 1.002f - 0.001f;
            }
        }
    }
}

// ---------------------------------------------------------------------------
extern "C" void kernel_launch(void* const* d_in, const int* in_sizes, int n_in,
                              void* d_out, int out_size, void* d_ws, size_t ws_size,
                              hipStream_t stream) {
    const float* means = (const float*)d_in[1];
    const float* stds  = (const float*)d_in[2];
    const float* dirs  = (const float*)d_in[3];
    const float* emb   = (const float*)d_in[5];
    const float* W1   = (const float*)d_in[6];
    const float* b1   = (const float*)d_in[7];
    const float* W2   = (const float*)d_in[8];
    const float* b2   = (const float*)d_in[9];
    const float* Wv0  = (const float*)d_in[10];
    const float* bv0  = (const float*)d_in[11];
    const float* Wv1  = (const float*)d_in[12];
    const float* bv1  = (const float*)d_in[13];
    const float* Wrgb = (const float*)d_in[14];
    const float* brgb = (const float*)d_in[15];

    const int N = in_sizes[1] / 18;  // means: [N,6,3]
    unsigned short* pack = (unsigned short*)d_ws;
    float* feats = (float*)((char*)d_ws + FEATS_BYTE_OFF);
    float* out   = (float*)d_out;    // rgb [N*3] then density [N]

    pack_kernel<<<(PU_TOTAL + 255) / 256, 256, 0, stream>>>(W1, W2, Wv0, Wv1, Wrgb, pack);

    dim3 gridA((N + 255) / 256, NLVL);
    hash_kernel<<<gridA, 256, 0, stream>>>(N, means, stds, emb, feats);

    density_kernel<<<(N + 255) / 256, 256, 0, stream>>>(N, feats, W1, b1, W2, b2,
                                                        out + (size_t)3 * N);

    mlp_mfma_kernel<<<N / 64, 256, 0, stream>>>(N, feats, dirs, pack,
                                                b1, b2, bv0, bv1, brgb, out);
}

// Round 4
// 925.389 us; speedup vs baseline: 2.9325x; 1.0158x over previous
//
#include <hip/hip_runtime.h>
#include <math.h>
#include <stdint.h>

typedef __attribute__((ext_vector_type(8))) short bf16x8;
typedef __attribute__((ext_vector_type(4))) float f32x4;

#define NLVL 10

constexpr int      kRes[NLVL]  = {16, 32, 64, 128, 256, 512, 1024, 2048, 4096, 8192};
constexpr unsigned kSize[NLVL] = {4920u, 35944u, 274632u, 2097152u, 2097152u,
                                  2097152u, 2097152u, 2097152u, 2097152u, 2097152u};
constexpr unsigned kOff[NLVL]  = {0u, 4920u, 40864u, 315496u, 2412648u,
                                  4509800u, 6606952u, 8704104u, 10801256u, 12898408u};

// Packed-weight layout in d_ws (ushort element offsets). Tiles 32(K)x16(N).
constexpr int PU_W1   = 0;
constexpr int PU_W2   = 4096;
constexpr int PU_WV0  = 20480;
constexpr int PU_WV1  = 94208;
constexpr int PU_WRGB = 233472;
constexpr int PU_TOTAL = 237568;
constexpr size_t FEATS_BYTE_OFF = (size_t)PU_TOTAL * 2;              // 475136
constexpr size_t EMBB_BYTE_OFF  = FEATS_BYTE_OFF + 131072ull * 160;  // +20.97MB

__device__ __forceinline__ unsigned short f2bf(float f) {
    unsigned u = __builtin_bit_cast(unsigned, f);
    u = u + 0x7FFFu + ((u >> 16) & 1u);
    return (unsigned short)(u >> 16);
}
__device__ __forceinline__ float bf_lo(unsigned u) {
    return __builtin_bit_cast(float, u << 16);
}
__device__ __forceinline__ float bf_hi(unsigned u) {
    return __builtin_bit_cast(float, u & 0xffff0000u);
}

// ---------------------------------------------------------------------------
// Weight pack kernel: f32 row-major [K][N] -> bf16 MFMA tile layout.
// ---------------------------------------------------------------------------
__global__ void __launch_bounds__(256) pack_kernel(
    const float* __restrict__ W1, const float* __restrict__ W2,
    const float* __restrict__ Wv0, const float* __restrict__ Wv1,
    const float* __restrict__ Wrgb, unsigned short* __restrict__ out) {
    int e = blockIdx.x * 256 + threadIdx.x;
    if (e >= PU_TOTAL) return;
    const float* W; int base, K, N, lg;
    if (e < PU_W2)        { W = W1;   base = PU_W1;   K = 40;  N = 64;  lg = 2; }
    else if (e < PU_WV0)  { W = W2;   base = PU_W2;   K = 64;  N = 256; lg = 4; }
    else if (e < PU_WV1)  { W = Wv0;  base = PU_WV0;  K = 283; N = 256; lg = 4; }
    else if (e < PU_WRGB) { W = Wv1;  base = PU_WV1;  K = 539; N = 256; lg = 4; }
    else                  { W = Wrgb; base = PU_WRGB; K = 256; N = 3;   lg = 0; }
    int le = e - base;
    int tile = le >> 9, r = le & 511, lane = r >> 3, j = r & 7;
    int kt = tile >> lg, nt = tile & ((1 << lg) - 1);
    int k = kt * 32 + ((lane >> 4) << 3) + j;
    int n = nt * 16 + (lane & 15);
    float v = (k < K && n < N) ? W[k * N + n] : 0.f;
    out[e] = f2bf(v);
}

// ---------------------------------------------------------------------------
// Embedding table fp32 -> bf16 (packed uint2 per 4-channel entry).
// ---------------------------------------------------------------------------
__global__ void __launch_bounds__(256) conv_kernel(int total,
                                                   const float4* __restrict__ emb,
                                                   uint2* __restrict__ out) {
    int stride = gridDim.x * 256;
    for (int e = blockIdx.x * 256 + threadIdx.x; e < total; e += stride) {
        float4 v = emb[e];
        unsigned a = (unsigned)f2bf(v.x) | ((unsigned)f2bf(v.y) << 16);
        unsigned b = (unsigned)f2bf(v.z) | ((unsigned)f2bf(v.w) << 16);
        out[e] = uint2{a, b};
    }
}

// ---------------------------------------------------------------------------
// Kernel A: hash-grid encode + erf weighting + mean. BF=true reads the
// L3-resident bf16 table (8B gathers); BF=false reads fp32 (fallback).
// ---------------------------------------------------------------------------
template <int LVL, bool BF>
__device__ __forceinline__ void hash_level(int i,
                                           const float* __restrict__ means,
                                           const float* __restrict__ stds,
                                           const float* __restrict__ emb,
                                           const uint2* __restrict__ embB,
                                           float* __restrict__ feats) {
    constexpr float    res = (float)kRes[LVL];
    constexpr unsigned sz  = kSize[LVL];
    const float* __restrict__ embL = emb + (size_t)kOff[LVL] * 4;
    const uint2* __restrict__ tbl  = embB + kOff[LVL];

    float a0 = 0.f, a1 = 0.f, a2 = 0.f, a3 = 0.f;
#pragma unroll 1
    for (int j = 0; j < 6; ++j) {
        const float* mp = means + ((size_t)i * 6 + j) * 3;
        float mx = mp[0], my = mp[1], mz = mp[2];
        float s = stds[i * 6 + j];
        float w = erff(1.0f / (2.8284271247461903f * s * res));

        float px = (mx + 1.0f) * 0.5f * res + 0.5f;
        float py = (my + 1.0f) * 0.5f * res + 0.5f;
        float pz = (mz + 1.0f) * 0.5f * res + 0.5f;
        float flx = floorf(px), fly = floorf(py), flz = floorf(pz);
        float fx = px - flx, fy = py - fly, fz = pz - flz;
        unsigned bx = (unsigned)(int)flx;
        unsigned by = (unsigned)(int)fly;
        unsigned bz = (unsigned)(int)flz;

        unsigned hx0 = bx,               hx1 = bx + 1u;
        unsigned hy0 = by * 2654435761u, hy1 = (by + 1u) * 2654435761u;
        unsigned hz0 = bz * 805459861u,  hz1 = (bz + 1u) * 805459861u;
        float wx0 = 1.f - fx, wy0 = 1.f - fy, wz0 = 1.f - fz;

#pragma unroll
        for (int c = 0; c < 8; ++c) {
            unsigned h = ((c & 1) ? hx1 : hx0) ^ ((c & 2) ? hy1 : hy0) ^
                         ((c & 4) ? hz1 : hz0);
            unsigned idx = h % sz;
            float g0, g1, g2, g3;
            if constexpr (BF) {
                const uint2 g8 = tbl[idx];
                g0 = bf_lo(g8.x); g1 = bf_hi(g8.x);
                g2 = bf_lo(g8.y); g3 = bf_hi(g8.y);
            } else {
                const float4 g = *reinterpret_cast<const float4*>(embL + (size_t)idx * 4);
                g0 = g.x; g1 = g.y; g2 = g.z; g3 = g.w;
            }
            float wc = w * ((c & 1) ? fx : wx0) * ((c & 2) ? fy : wy0) *
                       ((c & 4) ? fz : wz0);
            a0 = fmaf(wc, g0, a0);
            a1 = fmaf(wc, g1, a1);
            a2 = fmaf(wc, g2, a2);
            a3 = fmaf(wc, g3, a3);
        }
    }
    constexpr float inv6 = 1.0f / 6.0f;
    float4 o;
    o.x = a0 * inv6; o.y = a1 * inv6; o.z = a2 * inv6; o.w = a3 * inv6;
    *reinterpret_cast<float4*>(feats + (size_t)i * 40 + LVL * 4) = o;
}

template <bool BF>
__global__ void __launch_bounds__(256) hash_kernel(int N,
                                                   const float* __restrict__ means,
                                                   const float* __restrict__ stds,
                                                   const float* __restrict__ emb,
                                                   const uint2* __restrict__ embB,
                                                   float* __restrict__ feats) {
    int i = blockIdx.x * 256 + threadIdx.x;
    if (i >= N) return;
    switch (blockIdx.y) {
        case 0: hash_level<0, BF>(i, means, stds, emb, embB, feats); break;
        case 1: hash_level<1, BF>(i, means, stds, emb, embB, feats); break;
        case 2: hash_level<2, BF>(i, means, stds, emb, embB, feats); break;
        case 3: hash_level<3, BF>(i, means, stds, emb, embB, feats); break;
        case 4: hash_level<4, BF>(i, means, stds, emb, embB, feats); break;
        case 5: hash_level<5, BF>(i, means, stds, emb, embB, feats); break;
        case 6: hash_level<6, BF>(i, means, stds, emb, embB, feats); break;
        case 7: hash_level<7, BF>(i, means, stds, emb, embB, feats); break;
        case 8: hash_level<8, BF>(i, means, stds, emb, embB, feats); break;
        case 9: hash_level<9, BF>(i, means, stds, emb, embB, feats); break;
    }
}

// ---------------------------------------------------------------------------
// Kernel C: exact fp32 density path (layer1 + layer2 column 0 + softplus).
// ---------------------------------------------------------------------------
__global__ void __launch_bounds__(256) density_kernel(
    int N, const float* __restrict__ feats, const float* __restrict__ W1,
    const float* __restrict__ b1, const float* __restrict__ W2,
    const float* __restrict__ b2, float* __restrict__ dens) {
    __shared__ float sW1[2560];
    __shared__ float sb1[64];
    __shared__ float sw2[64];
    int t = threadIdx.x;
    for (int e = t; e < 2560; e += 256) sW1[e] = W1[e];
    if (t < 64) { sb1[t] = b1[t]; sw2[t] = W2[t * 256]; }
    __syncthreads();
    int i = blockIdx.x * 256 + t;
    if (i >= N) return;
    float f[40];
    const float4* fp = (const float4*)(feats + (size_t)i * 40);
#pragma unroll
    for (int q = 0; q < 10; ++q) {
        float4 v = fp[q];
        f[q * 4] = v.x; f[q * 4 + 1] = v.y; f[q * 4 + 2] = v.z; f[q * 4 + 3] = v.w;
    }
    float x0 = 0.f;
#pragma unroll
    for (int n = 0; n < 64; ++n) {
        float h = sb1[n];
#pragma unroll
        for (int k = 0; k < 40; ++k) h = fmaf(f[k], sW1[k * 64 + n], h);
        x0 = fmaf(fmaxf(h, 0.f), sw2[n], x0);
    }
    float z = x0 + b2[0] - 1.0f;
    dens[i] = (z > 20.f) ? z : log1pf(expf(z));
}

// ---------------------------------------------------------------------------
// Kernel B: fused MFMA MLP, col-split. 64 samples/block, 4 waves.
// Wave w computes N-col tiles [nt0, nt0+NT) for ALL 64 rows (4 row-tiles)
// -> each packed B tile is loaded once per block (4x less L2 traffic),
// reused across 4 row-tiles in registers.
// ---------------------------------------------------------------------------
template <int NT, int LG>
__device__ __forceinline__ void gemmCS(const unsigned short* __restrict__ act,
                                       int strideU, int kl8, int Kt,
                                       const unsigned short* __restrict__ Bsrc,
                                       int nt0, int lane, f32x4 (*acc)[NT]) {
    const int rlane = lane & 15;
#pragma unroll 2
    for (int kt = 0; kt < Kt; ++kt) {
        bf16x8 b[NT];
#pragma unroll
        for (int i = 0; i < NT; ++i)
            b[i] = *(const bf16x8*)(Bsrc + (((size_t)kt << LG) + nt0 + i) * 512 + lane * 8);
        bf16x8 a[4];
#pragma unroll
        for (int r = 0; r < 4; ++r)
            a[r] = *(const bf16x8*)(act + (size_t)(r * 16 + rlane) * strideU + kl8 + kt * 32);
#pragma unroll
        for (int r = 0; r < 4; ++r)
#pragma unroll
            for (int i = 0; i < NT; ++i)
                acc[r][i] = __builtin_amdgcn_mfma_f32_16x16x32_bf16(a[r], b[i], acc[r][i], 0, 0, 0);
    }
}

__global__ void __launch_bounds__(256) mlp_mfma_kernel(
    int N, const float* __restrict__ feats, const float* __restrict__ dirs,
    const unsigned short* __restrict__ pack,
    const float* __restrict__ b1, const float* __restrict__ b2,
    const float* __restrict__ bv0, const float* __restrict__ bv1,
    const float* __restrict__ brgb, float* __restrict__ rgb_out) {
    // row strides 296/264/72 ushorts: odd multiples of 16B -> <=2-way (free)
    // bank aliasing on ds_read_b128 A-frag reads.
    __shared__ __align__(16) unsigned short sInp[64][296]; // x[256] + dir_enc, pad->288
    __shared__ __align__(16) unsigned short sHH[64][264];  // v0/v1 out; early: feat+h1
    unsigned short* sFeatB = &sHH[0][0];                   // [64][72]
    unsigned short* sH1    = &sHH[0][0] + 4608;            // [64][72]

    const int t = threadIdx.x;
    const int w = t >> 6, lane = t & 63;
    const int s0 = blockIdx.x * 64;

    // ---- stage features -> bf16 [64][72], zero K-pad cols 40..63
    {
        int row = t & 63, c0 = (t >> 6) * 10;
        const float* src = feats + (size_t)(s0 + row) * 40 + c0;
#pragma unroll
        for (int c = 0; c < 10; ++c) sFeatB[row * 72 + c0 + c] = f2bf(src[c]);
        int z0 = 40 + (t >> 6) * 6;
#pragma unroll
        for (int c = 0; c < 6; ++c) sFeatB[row * 72 + z0 + c] = 0;
    }
    // ---- dir encoding
    if (t < 64) {
        const float* vp = dirs + (size_t)(s0 + t) * 3;
        float vx = vp[0], vy = vp[1], vz = vp[2];
        sInp[t][256] = f2bf(vx); sInp[t][257] = f2bf(vy); sInp[t][258] = f2bf(vz);
#pragma unroll
        for (int q = 0; q < 4; ++q) {
            float sc = (float)(1 << q);
            sInp[t][259 + q * 3 + 0] = f2bf(sinf(vx * sc));
            sInp[t][259 + q * 3 + 1] = f2bf(sinf(vy * sc));
            sInp[t][259 + q * 3 + 2] = f2bf(sinf(vz * sc));
            sInp[t][271 + q * 3 + 0] = f2bf(cosf(vx * sc));
            sInp[t][271 + q * 3 + 1] = f2bf(cosf(vy * sc));
            sInp[t][271 + q * 3 + 2] = f2bf(cosf(vz * sc));
        }
#pragma unroll
        for (int c = 283; c < 288; ++c) sInp[t][c] = 0;
    }
    __syncthreads();

    const int kl8  = (lane >> 4) << 3;             // k sub-offset (ushorts)
    const int rq0  = (lane >> 4) << 2;             // C-frag row sub-base
    const int col0 = lane & 15;                    // C-frag col within tile

    // ---- layer 1: feats(40->64p) @ W1 -> h1[64], relu. Wave w: col tile w.
    {
        f32x4 acc1[4][1];
#pragma unroll
        for (int r = 0; r < 4; ++r) acc1[r][0] = f32x4{0.f, 0.f, 0.f, 0.f};
        gemmCS<1, 2>(sFeatB, 72, kl8, 2, pack + PU_W1, w, lane, acc1);
        float bb = b1[w * 16 + col0];
#pragma unroll
        for (int r = 0; r < 4; ++r)
#pragma unroll
            for (int q = 0; q < 4; ++q)
                sH1[(size_t)(r * 16 + rq0 + q) * 72 + w * 16 + col0] =
                    f2bf(fmaxf(acc1[r][0][q] + bb, 0.f));
    }
    __syncthreads();

    f32x4 acc[4][4];
    // ---- layer 2: h1(64) @ W2 -> x[256] (no relu) -> sInp cols 0..255
    {
#pragma unroll
        for (int r = 0; r < 4; ++r)
#pragma unroll
            for (int i = 0; i < 4; ++i) acc[r][i] = f32x4{0.f, 0.f, 0.f, 0.f};
        gemmCS<4, 4>(sH1, 72, kl8, 2, pack + PU_W2, w * 4, lane, acc);
#pragma unroll
        for (int i = 0; i < 4; ++i) {
            float bb = b2[(w * 4 + i) * 16 + col0];
#pragma unroll
            for (int r = 0; r < 4; ++r)
#pragma unroll
                for (int q = 0; q < 4; ++q)
                    sInp[r * 16 + rq0 + q][(w * 4 + i) * 16 + col0] =
                        f2bf(acc[r][i][q] + bb);
        }
    }
    __syncthreads();

    // ---- view layer 0: inp(288p) @ Wv0 -> h[256], relu -> sHH
    {
#pragma unroll
        for (int r = 0; r < 4; ++r)
#pragma unroll
            for (int i = 0; i < 4; ++i) acc[r][i] = f32x4{0.f, 0.f, 0.f, 0.f};
        gemmCS<4, 4>(&sInp[0][0], 296, kl8, 9, pack + PU_WV0, w * 4, lane, acc);
        __syncthreads();  // sHH (feat/h1 aliases) fully dead before overwrite
#pragma unroll
        for (int i = 0; i < 4; ++i) {
            float bb = bv0[(w * 4 + i) * 16 + col0];
#pragma unroll
            for (int r = 0; r < 4; ++r)
#pragma unroll
                for (int q = 0; q < 4; ++q)
                    sHH[r * 16 + rq0 + q][(w * 4 + i) * 16 + col0] =
                        f2bf(fmaxf(acc[r][i][q] + bb, 0.f));
        }
    }
    __syncthreads();

    // ---- view layer 1: concat(h[256], inp[288p]) @ Wv1 -> relu -> sHH
    {
#pragma unroll
        for (int r = 0; r < 4; ++r)
#pragma unroll
            for (int i = 0; i < 4; ++i) acc[r][i] = f32x4{0.f, 0.f, 0.f, 0.f};
        gemmCS<4, 4>(&sHH[0][0], 264, kl8, 8, pack + PU_WV1, w * 4, lane, acc);
        gemmCS<4, 4>(&sInp[0][0], 296, kl8, 9, pack + PU_WV1 + 65536, w * 4, lane, acc);
        __syncthreads();  // all reads of sHH done before overwrite
#pragma unroll
        for (int i = 0; i < 4; ++i) {
            float bb = bv1[(w * 4 + i) * 16 + col0];
#pragma unroll
            for (int r = 0; r < 4; ++r)
#pragma unroll
                for (int q = 0; q < 4; ++q)
                    sHH[r * 16 + rq0 + q][(w * 4 + i) * 16 + col0] =
                        f2bf(fmaxf(acc[r][i][q] + bb, 0.f));
        }
    }
    __syncthreads();

    // ---- rgb head: h(256) @ Wrgb(256x3p16), sigmoid. Wave w: rows w*16..
    {
        f32x4 accR = f32x4{0.f, 0.f, 0.f, 0.f};
        const unsigned short* hRow = &sHH[0][0] + (size_t)(w * 16 + col0) * 264 + kl8;
        const unsigned short* Bsrc = pack + PU_WRGB;
#pragma unroll
        for (int kt = 0; kt < 8; ++kt) {
            bf16x8 a = *(const bf16x8*)(hRow + kt * 32);
            bf16x8 b = *(const bf16x8*)(Bsrc + (size_t)kt * 512 + lane * 8);
            accR = __builtin_amdgcn_mfma_f32_16x16x32_bf16(a, b, accR, 0, 0, 0);
        }
        if (col0 < 3) {
            float bb = brgb[col0];
#pragma unroll
            for (int q = 0; q < 4; ++q) {
                float v = accR[q] + bb;
                float sg = 1.f / (1.f + expf(-v));
                rgb_out[(size_t)(s0 + w * 16 + rq0 + q) * 3 + col0] = sg * 1.002f - 0.001f;
            }
        }
    }
}

// ---------------------------------------------------------------------------
extern "C" void kernel_launch(void* const* d_in, const int* in_sizes, int n_in,
                              void* d_out, int out_size, void* d_ws, size_t ws_size,
                              hipStream_t stream) {
    const float* means = (const float*)d_in[1];
    const float* stds  = (const float*)d_in[2];
    const float* dirs  = (const float*)d_in[3];
    const float* emb   = (const float*)d_in[5];
    const float* W1   = (const float*)d_in[6];
    const float* b1   = (const float*)d_in[7];
    const float* W2   = (const float*)d_in[8];
    const float* b2   = (const float*)d_in[9];
    const float* Wv0  = (const float*)d_in[10];
    const float* bv0  = (const float*)d_in[11];
    const float* Wv1  = (const float*)d_in[12];
    const float* bv1  = (const float*)d_in[13];
    const float* Wrgb = (const float*)d_in[14];
    const float* brgb = (const float*)d_in[15];

    const int N = in_sizes[1] / 18;        // means: [N,6,3]
    const int totalEmb = in_sizes[5] / 4;  // embeddings: [TOTAL,4]
    unsigned short* pack = (unsigned short*)d_ws;
    float* feats = (float*)((char*)d_ws + FEATS_BYTE_OFF);
    uint2* embB  = (uint2*)((char*)d_ws + EMBB_BYTE_OFF);
    const size_t needWs = EMBB_BYTE_OFF + (size_t)totalEmb * 8;
    const bool useBf = ws_size >= needWs;
    float* out   = (float*)d_out;          // rgb [N*3] then density [N]

    pack_kernel<<<(PU_TOTAL + 255) / 256, 256, 0, stream>>>(W1, W2, Wv0, Wv1, Wrgb, pack);

    dim3 gridA((N + 255) / 256, NLVL);
    if (useBf) {
        conv_kernel<<<2048, 256, 0, stream>>>(totalEmb, (const float4*)emb, embB);
        hash_kernel<true><<<gridA, 256, 0, stream>>>(N, means, stds, emb, embB, feats);
    } else {
        hash_kernel<false><<<gridA, 256, 0, stream>>>(N, means, stds, emb, embB, feats);
    }

    density_kernel<<<(N + 255) / 256, 256, 0, stream>>>(N, feats, W1, b1, W2, b2,
                                                        out + (size_t)3 * N);

    mlp_mfma_kernel<<<N / 64, 256, 0, stream>>>(N, feats, dirs, pack,
                                                b1, b2, bv0, bv1, brgb, out);
}